// Round 7
// baseline (532.035 us; speedup 1.0000x reference)
//
#include <hip/hip_runtime.h>
#include <hip/hip_bf16.h>
#include <stdint.h>

#define N_ROWS 8192
#define DIN 2048
#define DOUT 2048
#define NE 8

// ---- GEMM geometry: 320x256 tile, 2-barrier K-loop, counted lgkm/vmcnt ----
#define BM3 320
#define BN3 256
#define BK2 64
#define RT3 33            // static max row tiles: floor(8192/320) + 8
#define NBLK3 (8 * RT3)   // 264

#define GATE_BLKS (N_ROWS / 4)   // 2048
#define CONV_BLKS 2560

// ---- fallback geometry ----
#define BM 128
#define BN 128
#define BK 64
#define MAX_RT 71

typedef __bf16 bf16x8 __attribute__((ext_vector_type(8)));
typedef float f32x4 __attribute__((ext_vector_type(4)));

__device__ __forceinline__ uint32_t f2bf(float f) {
  uint32_t u = __builtin_bit_cast(uint32_t, f);
  uint32_t r = u + 0x7FFFu + ((u >> 16) & 1u);   // RNE
  return r >> 16;
}

__device__ __forceinline__ void gl2lds16(const void* g, void* l) {
  __builtin_amdgcn_global_load_lds(
      (const __attribute__((address_space(1))) unsigned int*)g,
      (__attribute__((address_space(3))) unsigned int*)l, 16, 0, 0);
}

// ---------------- gate (argmax, bit-identical math) + X->bf16 + We->bf16 fused ----------------
__global__ __launch_bounds__(256) void gate_conv_kernel(
    const float* __restrict__ cond, const float* __restrict__ Wp,
    const float* __restrict__ bp, const float* __restrict__ X,
    const float* __restrict__ We,
    int* __restrict__ idx, int* __restrict__ counts,
    __hip_bfloat16* __restrict__ Xb, __hip_bfloat16* __restrict__ Web)
{
  const int t = threadIdx.x;

  if (blockIdx.x >= GATE_BLKS) {
    // pure We-conversion blocks
    if (!Web) return;
    const size_t total = (size_t)NE * DOUT * DIN / 8;
    const size_t stride = (size_t)CONV_BLKS * 256;
    for (size_t c = (size_t)(blockIdx.x - GATE_BLKS) * 256 + t; c < total; c += stride) {
      float4 v0 = ((const float4*)We)[c * 2];
      float4 v1 = ((const float4*)We)[c * 2 + 1];
      uint4 o;
      o.x = f2bf(v0.x) | (f2bf(v0.y) << 16);
      o.y = f2bf(v0.z) | (f2bf(v0.w) << 16);
      o.z = f2bf(v1.x) | (f2bf(v1.y) << 16);
      o.w = f2bf(v1.z) | (f2bf(v1.w) << 16);
      ((uint4*)Web)[c] = o;
    }
    return;
  }

  __shared__ int lc[NE];
  if (t < NE) lc[t] = 0;

  const int lane = t & 63;
  const int wid  = t >> 6;
  const int row  = blockIdx.x * 4 + wid;

  double acc[NE];
  #pragma unroll
  for (int e = 0; e < NE; ++e) acc[e] = 0.0;

  const float4* crow = (const float4*)(cond + (size_t)row * DIN);
  const float4* wp4  = (const float4*)Wp;
  #pragma unroll
  for (int i = 0; i < DIN / 256; ++i) {
    float4 c = crow[i * 64 + lane];
    #pragma unroll
    for (int e = 0; e < NE; ++e) {
      float4 w = wp4[e * (DIN / 4) + i * 64 + lane];
      acc[e] += (double)c.x * w.x + (double)c.y * w.y
              + (double)c.z * w.z + (double)c.w * w.w;
    }
  }
  #pragma unroll
  for (int e = 0; e < NE; ++e) {
    double v = acc[e];
    #pragma unroll
    for (int off = 32; off > 0; off >>= 1) v += __shfl_down(v, off, 64);
    acc[e] = v;
  }
  __syncthreads();          // lc zeroed
  if (lane == 0) {
    int best = 0; double bv = acc[0] + (double)bp[0];
    #pragma unroll
    for (int e = 1; e < NE; ++e) {
      double v = acc[e] + (double)bp[e];
      if (v > bv) { bv = v; best = e; }
    }
    idx[row] = best;
    atomicAdd(&lc[best], 1);
  }

  if (Xb) {   // fused conversion of this block's 4 rows of X
    const float4* xs = (const float4*)(X + (size_t)blockIdx.x * 4 * DIN);
    uint4* xd = (uint4*)(Xb + (size_t)blockIdx.x * 4 * DIN);
    #pragma unroll
    for (int c = 0; c < 4; ++c) {
      int ch = t + c * 256;
      float4 v0 = xs[ch * 2];
      float4 v1 = xs[ch * 2 + 1];
      uint4 o;
      o.x = f2bf(v0.x) | (f2bf(v0.y) << 16);
      o.y = f2bf(v0.z) | (f2bf(v0.w) << 16);
      o.z = f2bf(v1.x) | (f2bf(v1.y) << 16);
      o.w = f2bf(v1.z) | (f2bf(v1.w) << 16);
      xd[ch] = o;
    }
  }

  __syncthreads();
  if (t < NE && lc[t] > 0) atomicAdd(&counts[t], lc[t]);
}

// ---------------- tiny exclusive scan over 8 counts ----------------
__global__ void scan_kernel(const int* __restrict__ counts, int* __restrict__ offsets) {
  if (threadIdx.x == 0 && blockIdx.x == 0) {
    int s = 0;
    for (int e = 0; e < NE; ++e) { offsets[e] = s; s += counts[e]; }
  }
}

// ---------------- block-aggregated scatter ----------------
__global__ __launch_bounds__(256) void scatter_kernel(
    const int* __restrict__ idx, const int* __restrict__ offsets,
    int* __restrict__ fill, int* __restrict__ rows)
{
  __shared__ int lc[NE], lb[NE];
  const int t = threadIdx.x;
  if (t < NE) lc[t] = 0;
  __syncthreads();
  int n = blockIdx.x * 256 + t;
  int e = idx[n];
  int my = atomicAdd(&lc[e], 1);
  __syncthreads();
  if (t < NE) lb[t] = (lc[t] > 0) ? atomicAdd(&fill[t], lc[t]) : 0;
  __syncthreads();
  rows[offsets[e] + lb[e] + my] = n;
}

// ---------------- grouped GEMM: 320x256, 2-barrier K-loop, counted lgkm/vmcnt ----------------
// LDS half-tiles: 1KB chunks (16 rows x 32 k). Within a chunk, dest position p (byte p*16)
// holds (row p&15... actually row p>>2? No:) -- position p holds row p>>2, k-slot
// ((p&3) ^ ((p>>3)&3)).  Read addr for MFMA lane (fr,g): fr*64 + ((g^((fr>>1)&3))<<4)
// -> each 16-lane group covers all 8 granule-columns 2-deep (2-way = free, m136).
__global__ __launch_bounds__(512, 1) void moe_gemm8(
    const __hip_bfloat16* __restrict__ Xb, const __hip_bfloat16* __restrict__ Web,
    const float* __restrict__ be, const int* __restrict__ counts,
    const int* __restrict__ rows, float* __restrict__ out)
{
  __shared__ __align__(16) __hip_bfloat16 Asm[2][2][160 * 64];   // 80 KB
  __shared__ __align__(16) __hip_bfloat16 Bsm[2][2][128 * 64];   // 64 KB
  __shared__ int rowid[BM3];

  // bijective XCD swizzle: 264 = 8*33
  const int bid = blockIdx.x;
  const int w = (bid & 7) * RT3 + (bid >> 3);
  const int ct = w / RT3;
  const int rt = w % RT3;

  int e = 0, racc = 0, cnt = 0, base = 0;
  for (; e < NE; ++e) {
    cnt = counts[e];
    int tiles = (cnt + BM3 - 1) / BM3;
    if (rt < racc + tiles) break;
    racc += tiles; base += cnt;
  }
  if (e == NE) return;
  const int row0 = (rt - racc) * BM3;
  const int tid = threadIdx.x;
  if (tid < BM3)
    rowid[tid] = (row0 + tid < cnt) ? rows[base + row0 + tid] : -1;
  __syncthreads();

  const int lane = tid & 63, wid = tid >> 6;
  const bool w4 = (wid < 4);
  const int wm = wid >> 2, wn = wid & 3;
  const int g = lane >> 4, fr = lane & 15;
  // swizzled read offset within a (R16,kk) 1KB chunk: 2-way bank spread
  const int rsw = fr * 64 + ((g ^ ((fr >> 1) & 3)) << 4);

  // ---- staging chunk assignment ----
  const int cA0 = w4 ? (3 * wid) : (12 + 2 * (wid - 4));
  const int cA1 = cA0 + 1;
  const int cA2 = cA0 + 2;        // only waves 0-3
  const int cB0 = 2 * wid, cB1 = cB0 + 1;

  const int aD0 = cA0 * 1024 + lane * 16;
  const int aD1 = cA1 * 1024 + lane * 16;
  const int aD2 = cA2 * 1024 + lane * 16;
  const int bD0 = cB0 * 1024 + lane * 16;
  const int bD1 = cB1 * 1024 + lane * 16;

  // dest position lane holds: row = lane>>2, k-slot = (lane&3) ^ ((lane>>3)&3)
  const int frs = lane >> 2;
  const int qx  = (lane & 3) ^ ((lane >> 3) & 3);
  const __hip_bfloat16 *aP[2][3], *bP[2][2];
  {
    const int cA[3] = {cA0, cA1, cA2};
    const int cB[2] = {cB0, cB1};
    #pragma unroll
    for (int h = 0; h < 2; ++h) {
      #pragma unroll
      for (int s = 0; s < 3; ++s) {
        int c = cA[s];
        int R = h * 160 + (c >> 1) * 16 + frs;
        int gr = rowid[R];
        if (gr < 0) gr = 0;
        aP[h][s] = Xb + (size_t)gr * DIN + (c & 1) * 32 + qx * 8;
      }
      #pragma unroll
      for (int s = 0; s < 2; ++s) {
        int c = cB[s];
        size_t wrow = (size_t)e * DOUT + ct * BN3 + h * 128 + (c >> 1) * 16 + frs;
        bP[h][s] = Web + wrow * DIN + (c & 1) * 32 + qx * 8;
      }
    }
  }

  f32x4 acc[2][2][5][2];
  #pragma unroll
  for (int a = 0; a < 2; ++a)
    #pragma unroll
    for (int b = 0; b < 2; ++b)
      #pragma unroll
      for (int m = 0; m < 5; ++m)
        #pragma unroll
        for (int n = 0; n < 2; ++n)
          acc[a][b][m][n] = 0.0f;

  bf16x8 av0[2][5], av1[2][5], bv[2][2][2];   // av[kk][mi], bv[nh][kk][ni]

#define STG_A(buf, h, kel) do {                                              \
    gl2lds16(aP[h][0] + (kel), (char*)&Asm[buf][h][0] + aD0);                \
    gl2lds16(aP[h][1] + (kel), (char*)&Asm[buf][h][0] + aD1);                \
    if (w4) gl2lds16(aP[h][2] + (kel), (char*)&Asm[buf][h][0] + aD2);        \
  } while (0)
#define STG_B(buf, h, kel) do {                                              \
    gl2lds16(bP[h][0] + (kel), (char*)&Bsm[buf][h][0] + bD0);                \
    gl2lds16(bP[h][1] + (kel), (char*)&Bsm[buf][h][0] + bD1); } while (0)

#define RD_A5(dst, cc, h, kk) do { const char* Ab_ = (const char*)&Asm[cc][h][0]; \
    _Pragma("unroll") for (int mi = 0; mi < 5; ++mi)                         \
      dst[mi] = *(const bf16x8*)(Ab_ + (wm * 5 + mi) * 2048 + (kk) * 1024 + rsw); } while (0)
#define RD_B2(cc, h, kk) do { const char* Bb_ = (const char*)&Bsm[cc][h][0]; \
    _Pragma("unroll") for (int ni = 0; ni < 2; ++ni)                         \
      bv[h][kk][ni] = *(const bf16x8*)(Bb_ + (wn * 2 + ni) * 2048 + (kk) * 1024 + rsw); } while (0)

#define BAR   __builtin_amdgcn_s_barrier()
#define SB0   __builtin_amdgcn_sched_barrier(0)
#define LGKMC(n) do { asm volatile("s_waitcnt lgkmcnt(" #n ")" ::: "memory"); \
                      __builtin_amdgcn_sched_barrier(0); } while (0)
#define VMCN  do { if (w4) { asm volatile("s_waitcnt vmcnt(10)" ::: "memory"); } \
                   else    { asm volatile("s_waitcnt vmcnt(8)"  ::: "memory"); } \
                   __builtin_amdgcn_sched_barrier(0); } while (0)
#define VMC0  do { asm volatile("s_waitcnt vmcnt(0)" ::: "memory");          \
                   __builtin_amdgcn_sched_barrier(0); } while (0)

#define MF10(avv, kk, mh, nh) do { __builtin_amdgcn_s_setprio(1);            \
    _Pragma("unroll") for (int mi = 0; mi < 5; ++mi)                         \
    _Pragma("unroll") for (int ni = 0; ni < 2; ++ni)                         \
      acc[mh][nh][mi][ni] = __builtin_amdgcn_mfma_f32_16x16x32_bf16(         \
          avv[mi], bv[nh][kk][ni], acc[mh][nh][mi][ni], 0, 0, 0);            \
    __builtin_amdgcn_s_setprio(0); } while (0)

  // per K-tile: issue reads in counted groups; MFMA runs while later reads drain.
  // 2 barriers: BAR1 (all buf-c reads retired -> t+2 staging may target c),
  //             BAR2 (tile t+1 staged data collectively visible).
#define TILE_BODY(cc, tt_) do {                                              \
    const int k2_ = ((tt_) + 2) * BK2;                                       \
    const bool s2_ = ((tt_) + 2 < T);                                        \
    RD_A5(av0[0], cc, 0, 0); RD_B2(cc, 0, 0); SB0;   /* 7 */                 \
    RD_A5(av0[1], cc, 0, 1); RD_B2(cc, 0, 1); SB0;   /* +7 = 14 */           \
    LGKMC(7);  MF10(av0[0], 0, 0, 0);                                        \
    RD_B2(cc, 1, 0); RD_B2(cc, 1, 1); SB0;           /* +4 <= 11 out */      \
    LGKMC(4);  MF10(av0[1], 1, 0, 0);                                        \
    RD_A5(av1[0], cc, 1, 0); RD_A5(av1[1], cc, 1, 1); SB0; /* +10 <= 14 */   \
    LGKMC(10); MF10(av0[0], 0, 0, 1); MF10(av0[1], 1, 0, 1);                 \
    LGKMC(0);  BAR;                                                          \
    if (s2_) { STG_A(cc, 0, k2_); STG_B(cc, 0, k2_);                         \
               STG_A(cc, 1, k2_); STG_B(cc, 1, k2_); }                       \
    MF10(av1[0], 0, 1, 0); MF10(av1[1], 1, 1, 0);                            \
    MF10(av1[0], 0, 1, 1); MF10(av1[1], 1, 1, 1);                            \
    if (s2_) { VMCN; } else { VMC0; }                                        \
    BAR; } while (0)

  const int T = DIN / BK2;    // 32

  // ---- prologue: stage tiles 0 and 1 ----
  STG_A(0, 0, 0);  STG_B(0, 0, 0);  STG_A(0, 1, 0);  STG_B(0, 1, 0);
  STG_A(1, 0, 64); STG_B(1, 0, 64); STG_A(1, 1, 64); STG_B(1, 1, 64);
  VMCN;                       // tile0 landed; tile1 in flight
  BAR;

  #pragma unroll 1
  for (int tt = 0; tt < T / 2; ++tt) {
    const int t2 = tt * 2;
    TILE_BODY(0, t2);
    TILE_BODY(1, t2 + 1);
  }

#undef STG_A
#undef STG_B
#undef RD_A5
#undef RD_B2
#undef MF10
#undef TILE_BODY

  // ---- epilogue: bias + scatter-store ----
  float beh[2][2];
  #pragma unroll
  for (int nh = 0; nh < 2; ++nh)
    #pragma unroll
    for (int ni = 0; ni < 2; ++ni)
      beh[nh][ni] = be[(size_t)e * DOUT + ct * BN3 + nh * 128 + wn * 32 + ni * 16 + fr];

  #pragma unroll
  for (int mh = 0; mh < 2; ++mh)
    #pragma unroll
    for (int mi = 0; mi < 5; ++mi)
      #pragma unroll
      for (int j = 0; j < 4; ++j) {
        int R = mh * 160 + wm * 80 + mi * 16 + g * 4 + j;
        int grow = rowid[R];
        if (grow < 0) continue;
        float* orow = out + (size_t)grow * DOUT + ct * BN3;
        #pragma unroll
        for (int nh = 0; nh < 2; ++nh)
          #pragma unroll
          for (int ni = 0; ni < 2; ++ni)
            orow[nh * 128 + wn * 32 + ni * 16 + fr] = acc[mh][nh][mi][ni][j] + beh[nh][ni];
      }
}

// ---------------- fallback grouped GEMM (reg-staged f32, known-good) ----------------
__global__ __launch_bounds__(256) void moe_gemm_fb(
    const float* __restrict__ X, const float* __restrict__ We,
    const float* __restrict__ be, const int* __restrict__ counts,
    const int* __restrict__ offsets, const int* __restrict__ rows,
    float* __restrict__ out)
{
  __shared__ __align__(16) unsigned char Asb[BM * BK * 2];
  __shared__ __align__(16) unsigned char Bsb[BN * BK * 2];
  __shared__ int rowid[BM];

  const int ct = blockIdx.x;
  const int rt = blockIdx.y;

  int e = 0, racc = 0, cnt = 0;
  for (; e < NE; ++e) {
    cnt = counts[e];
    int tiles = (cnt + BM - 1) / BM;
    if (rt < racc + tiles) break;
    racc += tiles;
  }
  if (e == NE) return;
  const int row0 = (rt - racc) * BM;
  const int base = offsets[e];

  if (threadIdx.x < BM) {
    int r = row0 + threadIdx.x;
    rowid[threadIdx.x] = (r < cnt) ? rows[base + r] : -1;
  }
  __syncthreads();

  const int t    = threadIdx.x;
  const int lane = t & 63;
  const int wv   = t >> 6;
  const int wr   = wv >> 1, wc = wv & 1;
  const int g    = lane >> 4, fr = lane & 15;
  const int srow = t >> 4;
  const int skq  = t & 15;

  f32x4 acc[4][4];
  #pragma unroll
  for (int m = 0; m < 4; ++m)
    #pragma unroll
    for (int n = 0; n < 4; ++n)
      acc[m][n] = 0.0f;

  const size_t bcol0 = (size_t)e * DOUT + (size_t)ct * BN;

  for (int k0 = 0; k0 < DIN; k0 += BK) {
    #pragma unroll
    for (int p = 0; p < 8; ++p) {
      int r = p * 16 + srow;
      int gr = rowid[r];
      float4 v = make_float4(0.f, 0.f, 0.f, 0.f);
      if (gr >= 0)
        v = *(const float4*)(X + (size_t)gr * DIN + k0 + skq * 4);
      uint32_t w0 = f2bf(v.x) | (f2bf(v.y) << 16);
      uint32_t w1 = f2bf(v.z) | (f2bf(v.w) << 16);
      int byte = r * (BK * 2) + ((skq * 8) ^ ((r & 7) << 4));
      *(uint2*)(Asb + byte) = make_uint2(w0, w1);
    }
    #pragma unroll
    for (int p = 0; p < 8; ++p) {
      int r = p * 16 + srow;
      float4 v = *(const float4*)(We + (bcol0 + r) * DIN + k0 + skq * 4);
      uint32_t w0 = f2bf(v.x) | (f2bf(v.y) << 16);
      uint32_t w1 = f2bf(v.z) | (f2bf(v.w) << 16);
      int byte = r * (BK * 2) + ((skq * 8) ^ ((r & 7) << 4));
      *(uint2*)(Bsb + byte) = make_uint2(w0, w1);
    }
    __syncthreads();

    #pragma unroll
    for (int kk = 0; kk < BK; kk += 32) {
      bf16x8 av[4], bv[4];
      #pragma unroll
      for (int m = 0; m < 4; ++m) {
        int r = wr * 64 + m * 16 + fr;
        int byte = r * (BK * 2) + ((((kk + g * 8) * 2)) ^ ((r & 7) << 4));
        av[m] = *(const bf16x8*)(Asb + byte);
      }
      #pragma unroll
      for (int n = 0; n < 4; ++n) {
        int c = wc * 64 + n * 16 + fr;
        int byte = c * (BK * 2) + ((((kk + g * 8) * 2)) ^ ((c & 7) << 4));
        bv[n] = *(const bf16x8*)(Bsb + byte);
      }
      #pragma unroll
      for (int m = 0; m < 4; ++m)
        #pragma unroll
        for (int n = 0; n < 4; ++n)
          acc[m][n] = __builtin_amdgcn_mfma_f32_16x16x32_bf16(av[m], bv[n], acc[m][n], 0, 0, 0);
    }
    __syncthreads();
  }

  const float* berow = be + (size_t)e * DOUT + (size_t)ct * BN + wc * 64;
  #pragma unroll
  for (int m = 0; m < 4; ++m) {
    #pragma unroll
    for (int j = 0; j < 4; ++j) {
      int r = wr * 64 + m * 16 + g * 4 + j;
      int grow = rowid[r];
      if (grow < 0) continue;
      float* orow = out + (size_t)grow * DOUT + (size_t)ct * BN + wc * 64;
      #pragma unroll
      for (int n = 0; n < 4; ++n)
        orow[n * 16 + fr] = acc[m][n][j] + berow[n * 16 + fr];
    }
  }
}

extern "C" void kernel_launch(void* const* d_in, const int* in_sizes, int n_in,
                              void* d_out, int out_size, void* d_ws, size_t ws_size,
                              hipStream_t stream) {
  const float* X    = (const float*)d_in[0];
  const float* cond = (const float*)d_in[1];
  const float* Wp   = (const float*)d_in[2];
  const float* bp   = (const float*)d_in[3];
  const float* We   = (const float*)d_in[4];
  const float* be   = (const float*)d_in[5];
  float* out = (float*)d_out;

  // ws layout
  int* counts  = (int*)d_ws;                       // [8]
  int* offsets = counts + 8;                       // [8]
  int* fill    = counts + 16;                      // [8]
  int* idx     = (int*)((char*)d_ws + 256);        // [8192]
  int* rows    = idx + N_ROWS;                     // [8192]
  const size_t XB_OFF  = 65792;
  const size_t WEB_OFF = XB_OFF + (size_t)N_ROWS * DIN * 2;       // +32 MB
  const size_t WS_NEED = WEB_OFF + (size_t)NE * DOUT * DIN * 2;   // ~96 MB

  hipMemsetAsync(d_ws, 0, 256, stream);

  if (ws_size >= WS_NEED) {
    __hip_bfloat16* Xb  = (__hip_bfloat16*)((char*)d_ws + XB_OFF);
    __hip_bfloat16* Web = (__hip_bfloat16*)((char*)d_ws + WEB_OFF);
    gate_conv_kernel<<<GATE_BLKS + CONV_BLKS, 256, 0, stream>>>(
        cond, Wp, bp, X, We, idx, counts, Xb, Web);
    scan_kernel<<<1, 64, 0, stream>>>(counts, offsets);
    scatter_kernel<<<N_ROWS / 256, 256, 0, stream>>>(idx, offsets, fill, rows);
    moe_gemm8<<<NBLK3, 512, 0, stream>>>(Xb, Web, be, counts, rows, out);
  } else {
    gate_conv_kernel<<<GATE_BLKS + CONV_BLKS, 256, 0, stream>>>(
        cond, Wp, bp, X, We, idx, counts, nullptr, nullptr);
    scan_kernel<<<1, 64, 0, stream>>>(counts, offsets);
    scatter_kernel<<<N_ROWS / 256, 256, 0, stream>>>(idx, offsets, fill, rows);
    moe_gemm_fb<<<dim3(DOUT / BN, MAX_RT), 256, 0, stream>>>(X, We, be, counts, offsets, rows, out);
  }
}

// Round 8
// 190.874 us; speedup vs baseline: 2.7874x; 2.7874x over previous
//
#include <hip/hip_runtime.h>
#include <hip/hip_bf16.h>
#include <stdint.h>

#define N_ROWS 8192
#define DIN 2048
#define DOUT 2048
#define NE 8

// ---- GEMM geometry: 320x256 tile, 8-phase, counted vmcnt, conflict-free LDS ----
#define BM3 320
#define BN3 256
#define BK2 64
#define RT3 33            // static max row tiles: floor(8192/320) + 8
#define NBLK3 (8 * RT3)   // 264

#define GATE_BLKS (N_ROWS / 4)   // 2048
#define CONV_BLKS 2560

// ---- fallback geometry ----
#define BM 128
#define BN 128
#define BK 64
#define MAX_RT 71

typedef __bf16 bf16x8 __attribute__((ext_vector_type(8)));
typedef float f32x4 __attribute__((ext_vector_type(4)));

__device__ __forceinline__ uint32_t f2bf(float f) {
  uint32_t u = __builtin_bit_cast(uint32_t, f);
  uint32_t r = u + 0x7FFFu + ((u >> 16) & 1u);   // RNE
  return r >> 16;
}

__device__ __forceinline__ void gl2lds16(const void* g, void* l) {
  __builtin_amdgcn_global_load_lds(
      (const __attribute__((address_space(1))) unsigned int*)g,
      (__attribute__((address_space(3))) unsigned int*)l, 16, 0, 0);
}

// ---------------- gate (argmax, bit-identical math) + X->bf16 + We->bf16 fused ----------------
__global__ __launch_bounds__(256) void gate_conv_kernel(
    const float* __restrict__ cond, const float* __restrict__ Wp,
    const float* __restrict__ bp, const float* __restrict__ X,
    const float* __restrict__ We,
    int* __restrict__ idx, int* __restrict__ counts,
    __hip_bfloat16* __restrict__ Xb, __hip_bfloat16* __restrict__ Web)
{
  const int t = threadIdx.x;

  if (blockIdx.x >= GATE_BLKS) {
    if (!Web) return;
    const size_t total = (size_t)NE * DOUT * DIN / 8;
    const size_t stride = (size_t)CONV_BLKS * 256;
    for (size_t c = (size_t)(blockIdx.x - GATE_BLKS) * 256 + t; c < total; c += stride) {
      float4 v0 = ((const float4*)We)[c * 2];
      float4 v1 = ((const float4*)We)[c * 2 + 1];
      uint4 o;
      o.x = f2bf(v0.x) | (f2bf(v0.y) << 16);
      o.y = f2bf(v0.z) | (f2bf(v0.w) << 16);
      o.z = f2bf(v1.x) | (f2bf(v1.y) << 16);
      o.w = f2bf(v1.z) | (f2bf(v1.w) << 16);
      ((uint4*)Web)[c] = o;
    }
    return;
  }

  __shared__ int lc[NE];
  if (t < NE) lc[t] = 0;

  const int lane = t & 63;
  const int wid  = t >> 6;
  const int row  = blockIdx.x * 4 + wid;

  double acc[NE];
  #pragma unroll
  for (int e = 0; e < NE; ++e) acc[e] = 0.0;

  const float4* crow = (const float4*)(cond + (size_t)row * DIN);
  const float4* wp4  = (const float4*)Wp;
  #pragma unroll
  for (int i = 0; i < DIN / 256; ++i) {
    float4 c = crow[i * 64 + lane];
    #pragma unroll
    for (int e = 0; e < NE; ++e) {
      float4 w = wp4[e * (DIN / 4) + i * 64 + lane];
      acc[e] += (double)c.x * w.x + (double)c.y * w.y
              + (double)c.z * w.z + (double)c.w * w.w;
    }
  }
  #pragma unroll
  for (int e = 0; e < NE; ++e) {
    double v = acc[e];
    #pragma unroll
    for (int off = 32; off > 0; off >>= 1) v += __shfl_down(v, off, 64);
    acc[e] = v;
  }
  __syncthreads();          // lc zeroed
  if (lane == 0) {
    int best = 0; double bv = acc[0] + (double)bp[0];
    #pragma unroll
    for (int e = 1; e < NE; ++e) {
      double v = acc[e] + (double)bp[e];
      if (v > bv) { bv = v; best = e; }
    }
    idx[row] = best;
    atomicAdd(&lc[best], 1);
  }

  if (Xb) {   // fused conversion of this block's 4 rows of X
    const float4* xs = (const float4*)(X + (size_t)blockIdx.x * 4 * DIN);
    uint4* xd = (uint4*)(Xb + (size_t)blockIdx.x * 4 * DIN);
    #pragma unroll
    for (int c = 0; c < 4; ++c) {
      int ch = t + c * 256;
      float4 v0 = xs[ch * 2];
      float4 v1 = xs[ch * 2 + 1];
      uint4 o;
      o.x = f2bf(v0.x) | (f2bf(v0.y) << 16);
      o.y = f2bf(v0.z) | (f2bf(v0.w) << 16);
      o.z = f2bf(v1.x) | (f2bf(v1.y) << 16);
      o.w = f2bf(v1.z) | (f2bf(v1.w) << 16);
      xd[ch] = o;
    }
  }

  __syncthreads();
  if (t < NE && lc[t] > 0) atomicAdd(&counts[t], lc[t]);
}

// ---------------- tiny exclusive scan over 8 counts ----------------
__global__ void scan_kernel(const int* __restrict__ counts, int* __restrict__ offsets) {
  if (threadIdx.x == 0 && blockIdx.x == 0) {
    int s = 0;
    for (int e = 0; e < NE; ++e) { offsets[e] = s; s += counts[e]; }
  }
}

// ---------------- block-aggregated scatter ----------------
__global__ __launch_bounds__(256) void scatter_kernel(
    const int* __restrict__ idx, const int* __restrict__ offsets,
    int* __restrict__ fill, int* __restrict__ rows)
{
  __shared__ int lc[NE], lb[NE];
  const int t = threadIdx.x;
  if (t < NE) lc[t] = 0;
  __syncthreads();
  int n = blockIdx.x * 256 + t;
  int e = idx[n];
  int my = atomicAdd(&lc[e], 1);
  __syncthreads();
  if (t < NE) lb[t] = (lc[t] > 0) ? atomicAdd(&fill[t], lc[t]) : 0;
  __syncthreads();
  rows[offsets[e] + lb[e] + my] = n;
}

// ---------------- grouped GEMM: 320x256, 8-phase (round-6 schedule), conflict-free LDS ----------
// LDS half-tiles: 1KB chunks = [16 rows][4 k-slots of 16B]. Physical k-slot j of row fr holds
// logical k-slot j ^ ((fr>>1)&3).  Read addr: fr*64 + ((g ^ ((fr>>1)&3))<<4) -> each 16-lane
// group covers all 8 4-bank granule columns 2-deep (2-way = free, m136). Validated r7: conflicts=0.
// Store side: gl2lds dest position lane holds row lane>>2, logical k-slot (lane&3)^((lane>>3)&3).
__global__ __launch_bounds__(512, 1) void moe_gemm8(
    const __hip_bfloat16* __restrict__ Xb, const __hip_bfloat16* __restrict__ Web,
    const float* __restrict__ be, const int* __restrict__ counts,
    const int* __restrict__ rows, float* __restrict__ out)
{
  __shared__ __align__(16) __hip_bfloat16 Asm[2][2][160 * 64];   // 80 KB
  __shared__ __align__(16) __hip_bfloat16 Bsm[2][2][128 * 64];   // 64 KB
  __shared__ int rowid[BM3];

  // bijective XCD swizzle: 264 = 8*33
  const int bid = blockIdx.x;
  const int w = (bid & 7) * RT3 + (bid >> 3);
  const int ct = w / RT3;
  const int rt = w % RT3;

  int e = 0, racc = 0, cnt = 0, base = 0;
  for (; e < NE; ++e) {
    cnt = counts[e];
    int tiles = (cnt + BM3 - 1) / BM3;
    if (rt < racc + tiles) break;
    racc += tiles; base += cnt;
  }
  if (e == NE) return;
  const int row0 = (rt - racc) * BM3;
  const int tid = threadIdx.x;
  if (tid < BM3)
    rowid[tid] = (row0 + tid < cnt) ? rows[base + row0 + tid] : -1;
  __syncthreads();   // rowid visible (no vmem in flight yet)

  const int lane = tid & 63, wid = tid >> 6;
  const bool w4 = (wid < 4);
  const int wm = wid >> 2, wn = wid & 3;
  const int g = lane >> 4, fr = lane & 15;
  // conflict-free read offset within a (R16,kk) 1KB chunk (validated: conflicts=0)
  const int rsw = fr * 64 + ((g ^ ((fr >> 1) & 3)) << 4);

  // ---- staging chunk assignment ----
  const int cA0 = w4 ? (3 * wid) : (12 + 2 * (wid - 4));
  const int cA1 = cA0 + 1;
  const int cA2 = cA0 + 2;        // only waves 0-3
  const int cB0 = 2 * wid, cB1 = cB0 + 1;

  const int aD0 = cA0 * 1024 + lane * 16;
  const int aD1 = cA1 * 1024 + lane * 16;
  const int aD2 = cA2 * 1024 + lane * 16;
  const int bD0 = cB0 * 1024 + lane * 16;
  const int bD1 = cB1 * 1024 + lane * 16;

  // dest position lane holds: row = lane>>2, logical k-slot = (lane&3) ^ ((lane>>3)&3)
  const int frs = lane >> 2;
  const int qx  = (lane & 3) ^ ((lane >> 3) & 3);
  const __hip_bfloat16 *aP[2][3], *bP[2][2];
  {
    const int cA[3] = {cA0, cA1, cA2};
    const int cB[2] = {cB0, cB1};
    #pragma unroll
    for (int h = 0; h < 2; ++h) {
      #pragma unroll
      for (int s = 0; s < 3; ++s) {
        int c = cA[s];
        int R = h * 160 + (c >> 1) * 16 + frs;
        int gr = rowid[R];
        if (gr < 0) gr = 0;
        aP[h][s] = Xb + (size_t)gr * DIN + (c & 1) * 32 + qx * 8;
      }
      #pragma unroll
      for (int s = 0; s < 2; ++s) {
        int c = cB[s];
        size_t wrow = (size_t)e * DOUT + ct * BN3 + h * 128 + (c >> 1) * 16 + frs;
        bP[h][s] = Web + wrow * DIN + (c & 1) * 32 + qx * 8;
      }
    }
  }

  f32x4 acc[2][2][5][2];
  #pragma unroll
  for (int a = 0; a < 2; ++a)
    #pragma unroll
    for (int b = 0; b < 2; ++b)
      #pragma unroll
      for (int m = 0; m < 5; ++m)
        #pragma unroll
        for (int n = 0; n < 2; ++n)
          acc[a][b][m][n] = 0.0f;

  bf16x8 av[2][5], bv[2][2];

#define STG_A(buf, h, kel) do {                                              \
    gl2lds16(aP[h][0] + (kel), (char*)&Asm[buf][h][0] + aD0);                \
    gl2lds16(aP[h][1] + (kel), (char*)&Asm[buf][h][0] + aD1);                \
    if (w4) gl2lds16(aP[h][2] + (kel), (char*)&Asm[buf][h][0] + aD2);        \
  } while (0)
#define STG_B(buf, h, kel) do {                                              \
    gl2lds16(bP[h][0] + (kel), (char*)&Bsm[buf][h][0] + bD0);                \
    gl2lds16(bP[h][1] + (kel), (char*)&Bsm[buf][h][0] + bD1); } while (0)

#define READ_A(c, h) do { const char* Ab_ = (const char*)&Asm[c][h][0];      \
    _Pragma("unroll") for (int kk = 0; kk < 2; ++kk)                         \
    _Pragma("unroll") for (int mi = 0; mi < 5; ++mi)                         \
      av[kk][mi] = *(const bf16x8*)(Ab_ + (wm * 5 + mi) * 2048 + kk * 1024 + rsw); } while (0)

#define READ_B(c, h) do { const char* Bb_ = (const char*)&Bsm[c][h][0];      \
    _Pragma("unroll") for (int kk = 0; kk < 2; ++kk)                         \
    _Pragma("unroll") for (int ni = 0; ni < 2; ++ni)                         \
      bv[kk][ni] = *(const bf16x8*)(Bb_ + (wn * 2 + ni) * 2048 + kk * 1024 + rsw); } while (0)

#define BAR   __builtin_amdgcn_s_barrier()
#define LGKM0 do { asm volatile("s_waitcnt lgkmcnt(0)" ::: "memory");        \
                   __builtin_amdgcn_sched_barrier(0); } while (0)
#define VMCN  do { if (w4) { asm volatile("s_waitcnt vmcnt(5)" ::: "memory"); } \
                   else    { asm volatile("s_waitcnt vmcnt(4)" ::: "memory"); } \
                   __builtin_amdgcn_sched_barrier(0); } while (0)
#define VMC0  do { asm volatile("s_waitcnt vmcnt(0)" ::: "memory");          \
                   __builtin_amdgcn_sched_barrier(0); } while (0)

#define MFMA_PH(mh, nh) do { __builtin_amdgcn_s_setprio(1);                  \
    _Pragma("unroll") for (int kk = 0; kk < 2; ++kk)                         \
    _Pragma("unroll") for (int mi = 0; mi < 5; ++mi)                         \
    _Pragma("unroll") for (int ni = 0; ni < 2; ++ni)                         \
      acc[mh][nh][mi][ni] = __builtin_amdgcn_mfma_f32_16x16x32_bf16(         \
          av[kk][mi], bv[kk][ni], acc[mh][nh][mi][ni], 0, 0, 0);             \
    __builtin_amdgcn_s_setprio(0); } while (0)

  // ---- prologue: tile0 all 4 halves + tile1 h0 halves ----
  STG_A(0, 0, 0);  STG_B(0, 0, 0);  STG_A(0, 1, 0);  STG_B(0, 1, 0);
  STG_A(1, 0, 64); STG_B(1, 0, 64);
  VMCN;                       // tile0 landed; tile1-h0 in flight
  BAR;

  const int T = DIN / BK2;    // 32
  #pragma unroll 1
  for (int t = 0; t < T; ++t) {
    const int c = t & 1, o = c ^ 1;
    const int k1 = (t + 1) * BK2, k2 = (t + 2) * BK2;
    const bool s1 = (t + 1 < T), s2 = (t + 2 < T);

    // p0: compute (mh0,nh0); stage Ah1(t+1)
    READ_A(c, 0); READ_B(c, 0);
    if (s1) STG_A(o, 1, k1);
    BAR; LGKM0;
    MFMA_PH(0, 0);
    BAR;

    // p1: compute (mh0,nh1), reuse av; stage Bh1(t+1)
    READ_B(c, 1);
    if (s1) STG_B(o, 1, k1);
    BAR; LGKM0;
    MFMA_PH(0, 1);
    BAR;

    // p2: compute (mh1,nh0); stage Ah0(t+2) (A[c][0] reads retired in p0)
    READ_A(c, 1); READ_B(c, 0);
    if (s2) STG_A(c, 0, k2);
    BAR; LGKM0;
    MFMA_PH(1, 0);
    BAR;

    // p3: compute (mh1,nh1); stage Bh0(t+2) (B[c][0] reads retired in p2)
    READ_B(c, 1);
    if (s2) STG_B(c, 0, k2);
    BAR; LGKM0;
    MFMA_PH(1, 1);
    if (s2) { VMCN; } else { VMC0; }   // counted: tile t+1 landed, t+2 stays in flight
    BAR;
  }

#undef STG_A
#undef STG_B
#undef READ_A
#undef READ_B
#undef MFMA_PH

  // ---- epilogue: bias + scatter-store ----
  float beh[2][2];
  #pragma unroll
  for (int nh = 0; nh < 2; ++nh)
    #pragma unroll
    for (int ni = 0; ni < 2; ++ni)
      beh[nh][ni] = be[(size_t)e * DOUT + ct * BN3 + nh * 128 + wn * 32 + ni * 16 + fr];

  #pragma unroll
  for (int mh = 0; mh < 2; ++mh)
    #pragma unroll
    for (int mi = 0; mi < 5; ++mi)
      #pragma unroll
      for (int j = 0; j < 4; ++j) {
        int R = mh * 160 + wm * 80 + mi * 16 + g * 4 + j;
        int grow = rowid[R];
        if (grow < 0) continue;
        float* orow = out + (size_t)grow * DOUT + ct * BN3;
        #pragma unroll
        for (int nh = 0; nh < 2; ++nh)
          #pragma unroll
          for (int ni = 0; ni < 2; ++ni)
            orow[nh * 128 + wn * 32 + ni * 16 + fr] = acc[mh][nh][mi][ni][j] + beh[nh][ni];
      }
}

// ---------------- fallback grouped GEMM (reg-staged f32, known-good) ----------------
__global__ __launch_bounds__(256) void moe_gemm_fb(
    const float* __restrict__ X, const float* __restrict__ We,
    const float* __restrict__ be, const int* __restrict__ counts,
    const int* __restrict__ offsets, const int* __restrict__ rows,
    float* __restrict__ out)
{
  __shared__ __align__(16) unsigned char Asb[BM * BK * 2];
  __shared__ __align__(16) unsigned char Bsb[BN * BK * 2];
  __shared__ int rowid[BM];

  const int ct = blockIdx.x;
  const int rt = blockIdx.y;

  int e = 0, racc = 0, cnt = 0;
  for (; e < NE; ++e) {
    cnt = counts[e];
    int tiles = (cnt + BM - 1) / BM;
    if (rt < racc + tiles) break;
    racc += tiles;
  }
  if (e == NE) return;
  const int row0 = (rt - racc) * BM;
  const int base = offsets[e];

  if (threadIdx.x < BM) {
    int r = row0 + threadIdx.x;
    rowid[threadIdx.x] = (r < cnt) ? rows[base + r] : -1;
  }
  __syncthreads();

  const int t    = threadIdx.x;
  const int lane = t & 63;
  const int wv   = t >> 6;
  const int wr   = wv >> 1, wc = wv & 1;
  const int g    = lane >> 4, fr = lane & 15;
  const int srow = t >> 4;
  const int skq  = t & 15;

  f32x4 acc[4][4];
  #pragma unroll
  for (int m = 0; m < 4; ++m)
    #pragma unroll
    for (int n = 0; n < 4; ++n)
      acc[m][n] = 0.0f;

  const size_t bcol0 = (size_t)e * DOUT + (size_t)ct * BN;

  for (int k0 = 0; k0 < DIN; k0 += BK) {
    #pragma unroll
    for (int p = 0; p < 8; ++p) {
      int r = p * 16 + srow;
      int gr = rowid[r];
      float4 v = make_float4(0.f, 0.f, 0.f, 0.f);
      if (gr >= 0)
        v = *(const float4*)(X + (size_t)gr * DIN + k0 + skq * 4);
      uint32_t w0 = f2bf(v.x) | (f2bf(v.y) << 16);
      uint32_t w1 = f2bf(v.z) | (f2bf(v.w) << 16);
      int byte = r * (BK * 2) + ((skq * 8) ^ ((r & 7) << 4));
      *(uint2*)(Asb + byte) = make_uint2(w0, w1);
    }
    #pragma unroll
    for (int p = 0; p < 8; ++p) {
      int r = p * 16 + srow;
      float4 v = *(const float4*)(We + (bcol0 + r) * DIN + k0 + skq * 4);
      uint32_t w0 = f2bf(v.x) | (f2bf(v.y) << 16);
      uint32_t w1 = f2bf(v.z) | (f2bf(v.w) << 16);
      int byte = r * (BK * 2) + ((skq * 8) ^ ((r & 7) << 4));
      *(uint2*)(Bsb + byte) = make_uint2(w0, w1);
    }
    __syncthreads();

    #pragma unroll
    for (int kk = 0; kk < BK; kk += 32) {
      bf16x8 av[4], bv[4];
      #pragma unroll
      for (int m = 0; m < 4; ++m) {
        int r = wr * 64 + m * 16 + fr;
        int byte = r * (BK * 2) + ((((kk + g * 8) * 2)) ^ ((r & 7) << 4));
        av[m] = *(const bf16x8*)(Asb + byte);
      }
      #pragma unroll
      for (int n = 0; n < 4; ++n) {
        int c = wc * 64 + n * 16 + fr;
        int byte = c * (BK * 2) + ((((kk + g * 8) * 2)) ^ ((c & 7) << 4));
        bv[n] = *(const bf16x8*)(Bsb + byte);
      }
      #pragma unroll
      for (int m = 0; m < 4; ++m)
        #pragma unroll
        for (int n = 0; n < 4; ++n)
          acc[m][n] = __builtin_amdgcn_mfma_f32_16x16x32_bf16(av[m], bv[n], acc[m][n], 0, 0, 0);
    }
    __syncthreads();
  }

  const float* berow = be + (size_t)e * DOUT + (size_t)ct * BN + wc * 64;
  #pragma unroll
  for (int m = 0; m < 4; ++m) {
    #pragma unroll
    for (int j = 0; j < 4; ++j) {
      int r = wr * 64 + m * 16 + g * 4 + j;
      int grow = rowid[r];
      if (grow < 0) continue;
      float* orow = out + (size_t)grow * DOUT + (size_t)ct * BN + wc * 64;
      #pragma unroll
      for (int n = 0; n < 4; ++n)
        orow[n * 16 + fr] = acc[m][n][j] + berow[n * 16 + fr];
    }
  }
}

extern "C" void kernel_launch(void* const* d_in, const int* in_sizes, int n_in,
                              void* d_out, int out_size, void* d_ws, size_t ws_size,
                              hipStream_t stream) {
  const float* X    = (const float*)d_in[0];
  const float* cond = (const float*)d_in[1];
  const float* Wp   = (const float*)d_in[2];
  const float* bp   = (const float*)d_in[3];
  const float* We   = (const float*)d_in[4];
  const float* be   = (const float*)d_in[5];
  float* out = (float*)d_out;

  // ws layout
  int* counts  = (int*)d_ws;                       // [8]
  int* offsets = counts + 8;                       // [8]
  int* fill    = counts + 16;                      // [8]
  int* idx     = (int*)((char*)d_ws + 256);        // [8192]
  int* rows    = idx + N_ROWS;                     // [8192]
  const size_t XB_OFF  = 65792;
  const size_t WEB_OFF = XB_OFF + (size_t)N_ROWS * DIN * 2;       // +32 MB
  const size_t WS_NEED = WEB_OFF + (size_t)NE * DOUT * DIN * 2;   // ~96 MB

  hipMemsetAsync(d_ws, 0, 256, stream);

  if (ws_size >= WS_NEED) {
    __hip_bfloat16* Xb  = (__hip_bfloat16*)((char*)d_ws + XB_OFF);
    __hip_bfloat16* Web = (__hip_bfloat16*)((char*)d_ws + WEB_OFF);
    gate_conv_kernel<<<GATE_BLKS + CONV_BLKS, 256, 0, stream>>>(
        cond, Wp, bp, X, We, idx, counts, Xb, Web);
    scan_kernel<<<1, 64, 0, stream>>>(counts, offsets);
    scatter_kernel<<<N_ROWS / 256, 256, 0, stream>>>(idx, offsets, fill, rows);
    moe_gemm8<<<NBLK3, 512, 0, stream>>>(Xb, Web, be, counts, rows, out);
  } else {
    gate_conv_kernel<<<GATE_BLKS + CONV_BLKS, 256, 0, stream>>>(
        cond, Wp, bp, X, We, idx, counts, nullptr, nullptr);
    scan_kernel<<<1, 64, 0, stream>>>(counts, offsets);
    scatter_kernel<<<N_ROWS / 256, 256, 0, stream>>>(idx, offsets, fill, rows);
    moe_gemm_fb<<<dim3(DOUT / BN, MAX_RT), 256, 0, stream>>>(X, We, be, counts, offsets, rows, out);
  }
}